// Round 1
// baseline (354.696 us; speedup 1.0000x reference)
//
#include <hip/hip_runtime.h>

#define NT 20        // time steps
#define BT 4096      // batch
#define HD 128       // hidden
#define RT 81920     // total rows = K*B = 20*4096
#define RB 128       // rows per block

typedef _Float16 half8 __attribute__((ext_vector_type(8)));
typedef _Float16 half2v __attribute__((ext_vector_type(2)));
typedef float f32x4 __attribute__((ext_vector_type(4)));
typedef float f32x2 __attribute__((ext_vector_type(2)));

#if defined(__has_builtin)
#  if __has_builtin(__builtin_amdgcn_fdot2)
#    define HAVE_FDOT2 1
#  endif
#endif

__device__ __forceinline__ float hsig(float x) {
  return fminf(fmaxf(x * 0.16666667f + 0.5f, 0.0f), 1.0f);
}
__device__ __forceinline__ float htanh(float x) {
  return fminf(fmaxf(x, -1.0f), 1.0f);
}

// load 8 consecutive f32, convert to f16x8 fragment
__device__ __forceinline__ half8 ldcvt8(const float* __restrict__ p) {
  f32x4 a = *(const f32x4*)p;
  f32x4 b = *(const f32x4*)(p + 4);
  half8 r;
  r[0] = (_Float16)a[0]; r[1] = (_Float16)a[1];
  r[2] = (_Float16)a[2]; r[3] = (_Float16)a[3];
  r[4] = (_Float16)b[0]; r[5] = (_Float16)b[1];
  r[6] = (_Float16)b[2]; r[7] = (_Float16)b[3];
  return r;
}

// Persistent LSTM decoder.
// Block: 512 threads = 8 waves, owns 128 consecutive rows r0..r0+127 (same k).
// Wave w owns hidden slice [16w,16w+16): its gate columns are 128n+16w+(l&15),
// n=0..3 = i,f,g,o, so the elementwise LSTM update is lane-local in the
// mfma_f32_16x16x32 D-layout (col=l&15, row=4*(l>>4)+reg).
// h lives in LDS (f16, double-buffered, XOR-swizzled byte^=(row&7)<<4),
// c lives in registers (f32). W_aug = [W_hh | W_ih | b_ih+b_hh | 0] (K=160)
// lives in 80 VGPRs per wave. out[t] is folded into step t+1's A-frag reads.
__global__ __launch_bounds__(512) void decoder_kernel(
    const float* __restrict__ obs, const float* __restrict__ pred,
    const float* __restrict__ Wm1, const float* __restrict__ bm1,
    const float* __restrict__ Wm2, const float* __restrict__ bm2,
    const float* __restrict__ W_ih, const float* __restrict__ W_hh,
    const float* __restrict__ b_ih, const float* __restrict__ b_hh,
    const float* __restrict__ W_out, const float* __restrict__ b_out,
    float* __restrict__ outp)
{
  __shared__ __align__(16) char lds[66048]; // 2x32KB h bufs + 512B W_out(f16)
  const int tid = threadIdx.x;
  const int w   = tid >> 6;       // wave id 0..7
  const int l   = tid & 63;
  const int l15 = l & 15;
  const int lg  = l >> 4;         // lane group 0..3
  const int r0  = blockIdx.x * RB;
  const int b0  = r0 & (BT - 1);

  char* const buf0 = lds;             // h buffer, parity 0
  char* const h1l  = lds + 32768;     // MLP mid activations (aliases buf parity 1)
  char* const wol  = lds + 65536;     // W_out as f16 [2][128]

  const f32x4 fzero = {0.f, 0.f, 0.f, 0.f};

  // precomputed A-read addressing: row = 16m + l15, byte = row*256 + ao[kt]
  const int rdmask = (l15 & 7) << 4;
  const int arow_base = l15 * 256;
  int ao[4];
#pragma unroll
  for (int kt = 0; kt < 4; ++kt) ao[kt] = (64 * kt + 16 * lg) ^ rdmask;
  // h-write addressing: row = 16m + 4lg + reg, col = 16w + l15
  int wbase[4];
#pragma unroll
  for (int reg = 0; reg < 4; ++reg) {
    int rr = 4 * lg + reg;
    wbase[reg] = rr * 256 + ((32 * w + 2 * l15) ^ ((rr & 7) << 4));
  }

  // stage W_out into LDS as f16 (broadcast reads in the out-fold)
  if (tid < 256) ((_Float16*)wol)[tid] = (_Float16)W_out[tid];

  // ---------------- Prologue: h0 = MLP(pred) ----------------
  // GEMM1: h1[128x64] = leaky_relu(pred_rows @ Wm1^T + bm1); wave w does rows 16w..16w+15
  {
    half8 a1[4], b1[4][4];
#pragma unroll
    for (int kt = 0; kt < 4; ++kt)
      a1[kt] = ldcvt8(pred + (size_t)(r0 + 16 * w + l15) * HD + kt * 32 + lg * 8);
#pragma unroll
    for (int n = 0; n < 4; ++n)
#pragma unroll
      for (int kt = 0; kt < 4; ++kt)
        b1[n][kt] = ldcvt8(Wm1 + (l15 + 16 * n) * HD + kt * 32 + lg * 8);
    f32x4 acc1[4];
#pragma unroll
    for (int n = 0; n < 4; ++n) acc1[n] = fzero;
#pragma unroll
    for (int kt = 0; kt < 4; ++kt)
#pragma unroll
      for (int n = 0; n < 4; ++n)
        acc1[n] = __builtin_amdgcn_mfma_f32_16x16x32_f16(a1[kt], b1[n][kt], acc1[n], 0, 0, 0);
#pragma unroll
    for (int n = 0; n < 4; ++n) {
      float bb = bm1[l15 + 16 * n];
#pragma unroll
      for (int reg = 0; reg < 4; ++reg) {
        int row = 16 * w + 4 * lg + reg;
        float v = acc1[n][reg] + bb;
        v = v >= 0.f ? v : 0.01f * v;   // leaky_relu slope 0.01
        *(_Float16*)(h1l + row * 128 + ((2 * (l15 + 16 * n)) ^ ((row & 7) << 4))) = (_Float16)v;
      }
    }
  }
  __syncthreads();
  // GEMM2: h0[128x128] = h1 @ Wm2^T + bm2 -> buf0 (f16, swizzled)
  {
    half8 a2[2], b2[8][2];
#pragma unroll
    for (int kt = 0; kt < 2; ++kt) {
      int row = 16 * w + l15;
      a2[kt] = *(const half8*)(h1l + row * 128 + ((64 * kt + 16 * lg) ^ rdmask));
    }
#pragma unroll
    for (int n = 0; n < 8; ++n)
#pragma unroll
      for (int kt = 0; kt < 2; ++kt)
        b2[n][kt] = ldcvt8(Wm2 + (l15 + 16 * n) * 64 + kt * 32 + lg * 8);
    f32x4 acc2[8];
#pragma unroll
    for (int n = 0; n < 8; ++n) acc2[n] = fzero;
#pragma unroll
    for (int kt = 0; kt < 2; ++kt)
#pragma unroll
      for (int n = 0; n < 8; ++n)
        acc2[n] = __builtin_amdgcn_mfma_f32_16x16x32_f16(a2[kt], b2[n][kt], acc2[n], 0, 0, 0);
#pragma unroll
    for (int n = 0; n < 8; ++n) {
      float bb = bm2[l15 + 16 * n];
#pragma unroll
      for (int reg = 0; reg < 4; ++reg) {
        int row = 16 * w + 4 * lg + reg;
        float v = acc2[n][reg] + bb;
        *(_Float16*)(buf0 + row * 256 + ((2 * (l15 + 16 * n)) ^ ((row & 7) << 4))) = (_Float16)v;
      }
    }
  }

  // ---------------- steady-state B fragments (kept in VGPRs) ----------------
  // W_aug[g, 0:128]=W_hh ; [128]=W_ih[:,0] ; [129]=W_ih[:,1] ; [130]=b_ih+b_hh
  half8 bW[4][5];
#pragma unroll
  for (int n = 0; n < 4; ++n) {
    int g = 128 * n + 16 * w + l15;
#pragma unroll
    for (int kt = 0; kt < 4; ++kt)
      bW[n][kt] = ldcvt8(W_hh + (size_t)g * HD + kt * 32 + lg * 8);
    half8 xb;
#pragma unroll
    for (int j = 0; j < 8; ++j) xb[j] = (_Float16)0.0f;
    if (lg == 0) {
      xb[0] = (_Float16)W_ih[g * 2 + 0];
      xb[1] = (_Float16)W_ih[g * 2 + 1];
      xb[2] = (_Float16)(b_ih[g] + b_hh[g]);
    }
    bW[n][4] = xb;
  }
  const float bo0 = b_out[0], bo1 = b_out[1];

  float cst[8][4];
#pragma unroll
  for (int m = 0; m < 8; ++m)
#pragma unroll
    for (int reg = 0; reg < 4; ++reg) cst[m][reg] = 0.f;

  __syncthreads();  // h0 visible; h1 reads done (step0 writes alias h1l)

  // ---------------- 20 recurrent steps ----------------
  for (int t = 0; t < NT; ++t) {
    char* const brd = lds + ((t & 1) << 15);
    char* const bwr = lds + ((((t & 1) ^ 1)) << 15);
    const float* obs_t = obs + (size_t)((t > 0) ? (t - 1) : 0) * (BT * 2);

#pragma unroll
    for (int pass = 0; pass < 2; ++pass) {
      f32x4 acc[4][4];
#pragma unroll
      for (int mm = 0; mm < 4; ++mm)
#pragma unroll
        for (int n = 0; n < 4; ++n) acc[mm][n] = fzero;

#pragma unroll
      for (int mm = 0; mm < 4; ++mm) {
        const int m = pass * 4 + mm;
        const bool doFold = (m == w) && (t > 0);
        float p0 = 0.f, p1 = 0.f;
#pragma unroll
        for (int kt = 0; kt < 5; ++kt) {
          half8 a;
          if (kt < 4) {
            a = *(const half8*)(brd + m * 4096 + arow_base + ao[kt]);
            if (doFold) {  // out[t-1] = h(t-1) @ W_out^T, folded into A-reads
              const half8 w0 = *(const half8*)(wol + 0   + kt * 64 + lg * 16);
              const half8 w1 = *(const half8*)(wol + 256 + kt * 64 + lg * 16);
#pragma unroll
              for (int pp = 0; pp < 4; ++pp) {
#ifdef HAVE_FDOT2
                half2v ha; ha[0] = a[2 * pp]; ha[1] = a[2 * pp + 1];
                half2v wa; wa[0] = w0[2 * pp]; wa[1] = w0[2 * pp + 1];
                half2v wb; wb[0] = w1[2 * pp]; wb[1] = w1[2 * pp + 1];
                p0 = __builtin_amdgcn_fdot2(ha, wa, p0, false);
                p1 = __builtin_amdgcn_fdot2(ha, wb, p1, false);
#else
                float h0f = (float)a[2 * pp], h1f = (float)a[2 * pp + 1];
                p0 = fmaf(h0f, (float)w0[2 * pp], p0);
                p0 = fmaf(h1f, (float)w0[2 * pp + 1], p0);
                p1 = fmaf(h0f, (float)w1[2 * pp], p1);
                p1 = fmaf(h1f, (float)w1[2 * pp + 1], p1);
#endif
              }
            }
          } else {
            // K-augmentation tile: A = [x0, x1, 1, 0...] on lane group 0
            half8 x8;
#pragma unroll
            for (int j = 0; j < 8; ++j) x8[j] = (_Float16)0.0f;
            if (lg == 0) {
              f32x2 xv = *(const f32x2*)(obs_t + (size_t)(b0 + 16 * m + l15) * 2);
              x8[0] = (_Float16)xv[0];
              x8[1] = (_Float16)xv[1];
              x8[2] = (_Float16)1.0f;
            }
            a = x8;
          }
#pragma unroll
          for (int n = 0; n < 4; ++n)
            acc[mm][n] = __builtin_amdgcn_mfma_f32_16x16x32_f16(a, bW[n][kt], acc[mm][n], 0, 0, 0);
        }
        if (doFold) {
          p0 += __shfl_xor(p0, 16, 64); p0 += __shfl_xor(p0, 32, 64);
          p1 += __shfl_xor(p1, 16, 64); p1 += __shfl_xor(p1, 32, 64);
          if (l < 16) {
            f32x2 v; v[0] = p0 + bo0; v[1] = p1 + bo1;
            *(f32x2*)(outp + (size_t)(t - 1) * (RT * 2) + (size_t)(r0 + 16 * w + l) * 2) = v;
          }
        }
      }

      // elementwise LSTM update (lane-local), write h_new to other buffer
#pragma unroll
      for (int mm = 0; mm < 4; ++mm) {
        const int m = pass * 4 + mm;
#pragma unroll
        for (int reg = 0; reg < 4; ++reg) {
          float ig = acc[mm][0][reg];
          float fg = acc[mm][1][reg];
          float gg = acc[mm][2][reg];
          float og = acc[mm][3][reg];
          float cc = cst[m][reg];
          float cn = hsig(fg) * cc + hsig(ig) * htanh(gg);
          cst[m][reg] = cn;
          float hn = hsig(og) * htanh(cn);
          *(_Float16*)(bwr + m * 4096 + wbase[reg]) = (_Float16)hn;
        }
      }
    }
    __syncthreads();
  }

  // ---------------- epilogue: out[19] from h(19) (in buf parity 0) ----------------
  {
    const int m = w;
    float p0 = 0.f, p1 = 0.f;
#pragma unroll
    for (int kt = 0; kt < 4; ++kt) {
      half8 a = *(const half8*)(buf0 + m * 4096 + arow_base + ao[kt]);
      const half8 w0 = *(const half8*)(wol + 0   + kt * 64 + lg * 16);
      const half8 w1 = *(const half8*)(wol + 256 + kt * 64 + lg * 16);
#pragma unroll
      for (int pp = 0; pp < 4; ++pp) {
#ifdef HAVE_FDOT2
        half2v ha; ha[0] = a[2 * pp]; ha[1] = a[2 * pp + 1];
        half2v wa; wa[0] = w0[2 * pp]; wa[1] = w0[2 * pp + 1];
        half2v wb; wb[0] = w1[2 * pp]; wb[1] = w1[2 * pp + 1];
        p0 = __builtin_amdgcn_fdot2(ha, wa, p0, false);
        p1 = __builtin_amdgcn_fdot2(ha, wb, p1, false);
#else
        float h0f = (float)a[2 * pp], h1f = (float)a[2 * pp + 1];
        p0 = fmaf(h0f, (float)w0[2 * pp], p0);
        p0 = fmaf(h1f, (float)w0[2 * pp + 1], p0);
        p1 = fmaf(h0f, (float)w1[2 * pp], p1);
        p1 = fmaf(h1f, (float)w1[2 * pp + 1], p1);
#endif
      }
    }
    p0 += __shfl_xor(p0, 16, 64); p0 += __shfl_xor(p0, 32, 64);
    p1 += __shfl_xor(p1, 16, 64); p1 += __shfl_xor(p1, 32, 64);
    if (l < 16) {
      f32x2 v; v[0] = p0 + bo0; v[1] = p1 + bo1;
      *(f32x2*)(outp + (size_t)19 * (RT * 2) + (size_t)(r0 + 16 * w + l) * 2) = v;
    }
  }
}

extern "C" void kernel_launch(void* const* d_in, const int* in_sizes, int n_in,
                              void* d_out, int out_size, void* d_ws, size_t ws_size,
                              hipStream_t stream) {
  const float* obs   = (const float*)d_in[0];
  const float* pred  = (const float*)d_in[1];
  const float* Wm1   = (const float*)d_in[2];
  const float* bm1   = (const float*)d_in[3];
  const float* Wm2   = (const float*)d_in[4];
  const float* bm2   = (const float*)d_in[5];
  const float* W_ih  = (const float*)d_in[6];
  const float* W_hh  = (const float*)d_in[7];
  const float* b_ih  = (const float*)d_in[8];
  const float* b_hh  = (const float*)d_in[9];
  const float* W_out = (const float*)d_in[10];
  const float* b_out = (const float*)d_in[11];

  decoder_kernel<<<RT / RB, 512, 0, stream>>>(
      obs, pred, Wm1, bm1, Wm2, bm2, W_ih, W_hh, b_ih, b_hh, W_out, b_out,
      (float*)d_out);
}